// Round 7
// baseline (17727.838 us; speedup 1.0000x reference)
//
#include <hip/hip_runtime.h>
#include <math.h>

#define QQ 512
#define NN 1000
#define HHID 1024
#define HPAD 1024   // padded row stride for h trajectories
#define CCON 128
#define G4 4000
#define LAYERS 8
#define LBLK 63     // ceil(1000/16) blocks per layer, 1024 thr, 1 neuron/wave
#define TOTBLK (LAYERS * LBLK)  // 504 — co-resident at 2 blocks/CU

__device__ inline float wred_min(float v){ for(int o=32;o;o>>=1) v=fminf(v,__shfl_xor(v,o)); return v; }
__device__ inline float wred_max(float v){ for(int o=32;o;o>>=1) v=fmaxf(v,__shfl_xor(v,o)); return v; }
__device__ inline float wred_sum(float v){ for(int o=32;o;o>>=1) v+=__shfl_xor(v,o); return v; }

// C[M,R] = A[M,K] @ B[R,K]^T + bias1[r] + bias2[r]; A row stride = lda.
__global__ __launch_bounds__(256) void gemm_nt(
    const float* __restrict__ A, const float* __restrict__ B,
    const float* __restrict__ bias1, const float* __restrict__ bias2,
    float* __restrict__ C, int M, int K, int R, int lda) {
  __shared__ float As[16][65];
  __shared__ float Bs[16][65];
  int tid = threadIdx.x;
  int tx = tid & 15, ty = tid >> 4;
  int m0 = blockIdx.y * 64, r0 = blockIdx.x * 64;
  float acc[4][4] = {};
  for (int k0 = 0; k0 < K; k0 += 16) {
#pragma unroll
    for (int i = 0; i < 4; i++) {
      int idx = tid + 256 * i;
      int ml = idx >> 4, kl = idx & 15;
      int m = m0 + ml, k = k0 + kl;
      As[kl][ml] = (m < M && k < K) ? A[(size_t)m * lda + k] : 0.f;
      int r = r0 + ml;
      Bs[kl][ml] = (r < R && k < K) ? B[(size_t)r * K + k] : 0.f;
    }
    __syncthreads();
#pragma unroll
    for (int kk = 0; kk < 16; kk++) {
      float a[4], b[4];
#pragma unroll
      for (int i = 0; i < 4; i++) a[i] = As[kk][ty * 4 + i];
#pragma unroll
      for (int j = 0; j < 4; j++) b[j] = Bs[kk][tx * 4 + j];
#pragma unroll
      for (int i = 0; i < 4; i++)
#pragma unroll
        for (int j = 0; j < 4; j++) acc[i][j] += a[i] * b[j];
    }
    __syncthreads();
  }
#pragma unroll
  for (int i = 0; i < 4; i++) {
    int m = m0 + ty * 4 + i;
    if (m >= M) continue;
#pragma unroll
    for (int j = 0; j < 4; j++) {
      int r = r0 + tx * 4 + j;
      if (r >= R) continue;
      float v = acc[i][j];
      if (bias1) v += bias1[r];
      if (bias2) v += bias2[r];
      C[(size_t)m * R + r] = v;
    }
  }
}

// All 8 layers x 512 steps in ONE kernel: dataflow diagonal pipeline.
// Block (layer, blk) owns 16 neurons of `layer`; wave w = neuron blk*16+w.
// h_l[t] needs h_l[t-1] (own layer) and h_{l-1}[t] (prev layer) -> critical
// chain is 512+7 stages instead of 8*512 steps. Layers>=1 compute the
// input-side matvec in-kernel (W_ih rows in 64 extra VGPRs). Cross-block
// handoff: relaxed agent-scope (sc1) loads/stores only, stamped per-block
// flags (flag = t+1 after h[t] published). NO fences (agent acquire fence =
// buffer_inv = full L2 invalidate, ~10us/step -- round-3 lesson).
__global__ __launch_bounds__(1024, 8) void lstm_pipeline(
    const float* __restrict__ P,     // [QQ, G4] layer-0 input gates (bias in)
    const float* __restrict__ Whh0,  // [G4, NN]
    const float* __restrict__ Wih,   // [7, G4, NN]
    const float* __restrict__ Whh,   // [7, G4, NN]
    const float* __restrict__ bih,   // [7, G4]
    const float* __restrict__ bhh,   // [7, G4]
    float* __restrict__ H,           // [LAYERS][QQ][HPAD]
    int* __restrict__ flag) {        // [LAYERS*64] zeroed before launch
  __shared__ float hsA[1024];  // h_{l-1}[t]   (stays 0 for layer 0)
  __shared__ float hsB[1024];  // h_l[t-1]     (stays 0 until t>=1)
  int tid = threadIdx.x;
  int wave = tid >> 6, lane = tid & 63;
  int layer = blockIdx.x / LBLK;
  int blk = blockIdx.x - layer * LBLK;
  int n = blk * 16 + wave;
  bool active = (n < NN);

  const float* WhhL = (layer == 0) ? Whh0 : Whh + (size_t)(layer - 1) * G4 * NN;
  const float* WihL = Wih + (size_t)(layer - 1) * G4 * NN;  // layer>=1 only
  float* Hout = H + (size_t)layer * QQ * HPAD;
  const float* Hin = H + (size_t)(layer - 1) * QQ * HPAD;   // layer>=1 only
  int* fown = flag + layer * 64;
  int* fprev = flag + (layer - 1) * 64;

  // Preload weights: whh_r always; wih_r + fused bias for layers >= 1.
  float whh_r[4][16], wih_r[4][16];
  float pb[4] = {0.f, 0.f, 0.f, 0.f};
#pragma unroll
  for (int q = 0; q < 4; q++)
#pragma unroll
    for (int it = 0; it < 16; it++) { whh_r[q][it] = 0.f; wih_r[q][it] = 0.f; }
  if (active) {
#pragma unroll
    for (int q = 0; q < 4; q++) {
      const float* wr = WhhL + (size_t)(q * NN + n) * NN;
#pragma unroll
      for (int it = 0; it < 16; it++) {
        int k = it * 64 + lane;
        if (k < NN) whh_r[q][it] = wr[k];
      }
    }
    if (layer > 0) {
#pragma unroll
      for (int q = 0; q < 4; q++) {
        const float* wr = WihL + (size_t)(q * NN + n) * NN;
#pragma unroll
        for (int it = 0; it < 16; it++) {
          int k = it * 64 + lane;
          if (k < NN) wih_r[q][it] = wr[k];
        }
        pb[q] = bih[(size_t)(layer - 1) * G4 + q * NN + n] +
                bhh[(size_t)(layer - 1) * G4 + q * NN + n];
      }
    }
  }
  hsA[tid] = 0.f;
  hsB[tid] = 0.f;
  __syncthreads();

  float creg = 0.f;  // cell state, register-resident for all 512 steps

  for (int t = 0; t < QQ; t++) {
    // Layer 0: prefetch this step's input gates before waiting.
    float p0 = 0.f, p1 = 0.f, p2 = 0.f, p3 = 0.f;
    if (layer == 0 && active) {
      const float* pt = P + (size_t)t * G4;
      p0 = pt[n]; p1 = pt[NN + n]; p2 = pt[2 * NN + n]; p3 = pt[3 * NN + n];
    }
    // Wait: own layer published h[t-1] (flag >= t) AND prev layer published
    // h[t] (flag >= t+1). Threads 0..62 check own, 64..126 check prev.
    if (t > 0 || layer > 0) {
      for (;;) {
        int ok = 1;
        if (tid < LBLK) {
          if (t > 0)
            ok = (__hip_atomic_load(&fown[tid], __ATOMIC_RELAXED,
                                    __HIP_MEMORY_SCOPE_AGENT) >= t);
        } else if (tid >= 64 && tid < 64 + LBLK) {
          if (layer > 0)
            ok = (__hip_atomic_load(&fprev[tid - 64], __ATOMIC_RELAXED,
                                    __HIP_MEMORY_SCOPE_AGENT) >= t + 1);
        }
        if (__syncthreads_and(ok)) break;
        __builtin_amdgcn_s_sleep(2);
      }
      // Gather dependency rows into LDS (sc1 loads bypass stale L2).
      if (layer > 0 && tid < NN)
        hsA[tid] = __hip_atomic_load(&Hin[(size_t)t * HPAD + tid],
                                     __ATOMIC_RELAXED, __HIP_MEMORY_SCOPE_AGENT);
      if (t > 0 && tid < NN)
        hsB[tid] = __hip_atomic_load(&Hout[(size_t)(t - 1) * HPAD + tid],
                                     __ATOMIC_RELAXED, __HIP_MEMORY_SCOPE_AGENT);
      __syncthreads();
    }
    if (active) {
      float a0 = 0.f, a1 = 0.f, a2 = 0.f, a3 = 0.f;
#pragma unroll
      for (int it = 0; it < 16; it++) {
        float ha = hsA[it * 64 + lane];  // 0 for layer 0
        float hb = hsB[it * 64 + lane];  // 0 at t == 0
        a0 += wih_r[0][it] * ha + whh_r[0][it] * hb;
        a1 += wih_r[1][it] * ha + whh_r[1][it] * hb;
        a2 += wih_r[2][it] * ha + whh_r[2][it] * hb;
        a3 += wih_r[3][it] * ha + whh_r[3][it] * hb;
      }
#pragma unroll
      for (int o = 32; o; o >>= 1) {
        a0 += __shfl_xor(a0, o);
        a1 += __shfl_xor(a1, o);
        a2 += __shfl_xor(a2, o);
        a3 += __shfl_xor(a3, o);
      }
      float g0, g1, g2, g3;
      if (layer == 0) { g0 = a0 + p0; g1 = a1 + p1; g2 = a2 + p2; g3 = a3 + p3; }
      else            { g0 = a0 + pb[0]; g1 = a1 + pb[1]; g2 = a2 + pb[2]; g3 = a3 + pb[3]; }
      float ii = 1.f / (1.f + expf(-g0));
      float ff = 1.f / (1.f + expf(-g1));
      float gg = tanhf(g2);
      float oo = 1.f / (1.f + expf(-g3));
      creg = ff * creg + ii * gg;
      float h = oo * tanhf(creg);
      if (lane == 0)
        __hip_atomic_store(&Hout[(size_t)t * HPAD + n], h, __ATOMIC_RELAXED,
                           __HIP_MEMORY_SCOPE_AGENT);
    }
    __syncthreads();  // each wave drains vmcnt(0) before s_barrier -> h @ LLC
    if (tid == 0)
      __hip_atomic_store(&fown[blk], t + 1, __ATOMIC_RELAXED,
                         __HIP_MEMORY_SCOPE_AGENT);
  }
}

// Per-timestep output: min/max normalize + floored exp IRF. One block per t.
__global__ __launch_bounds__(256) void epilogue_out(
    const float* __restrict__ H7,   // [QQ, HPAD]
    const float* __restrict__ Wlin, const float* __restrict__ blin,
    const int* __restrict__ ccol, const float* __restrict__ Dnz,
    float* __restrict__ out,        // [QQ, NN]
    float* __restrict__ irbuf, float* __restrict__ mnirbuf) {
  int t = blockIdx.x, tid = threadIdx.x;
  int wave = tid >> 6, lane = tid & 63;
  __shared__ float hbuf[NN];
  __shared__ float smin[4], smax[4];
  __shared__ float bc[2];
  float lmin = 3.4e38f, lmax = -3.4e38f;
  for (int i = tid; i < NN; i += 256) {
    float v = H7[(size_t)t * HPAD + i];
    hbuf[i] = v;
    lmin = fminf(lmin, v); lmax = fmaxf(lmax, v);
  }
  lmin = wred_min(lmin); lmax = wred_max(lmax);
  if (lane == 0) { smin[wave] = lmin; smax[wave] = lmax; }
  __syncthreads();
  if (tid == 0) {
    bc[0] = fminf(fminf(smin[0], smin[1]), fminf(smin[2], smin[3]));
    bc[1] = fmaxf(fmaxf(smax[0], smax[1]), fmaxf(smax[2], smax[3]));
  }
  __syncthreads();
  float hmn = bc[0], hmx = bc[1];
  float clo = 3.4e38f, chi = -3.4e38f;
  if (tid < CCON) {
    float w = Wlin[tid], b = blin[tid];
    clo = b + fminf(w * hmn, w * hmx);
    chi = b + fmaxf(w * hmn, w * hmx);
  }
  clo = wred_min(clo); chi = wred_max(chi);
  __syncthreads();  // smin/smax reused below
  if (lane == 0) { smin[wave] = clo; smax[wave] = chi; }
  __syncthreads();
  if (tid == 0) {
    float mn = fminf(fminf(smin[0], smin[1]), fminf(smin[2], smin[3]));
    float mx = fmaxf(fmaxf(smax[0], smax[1]), fmaxf(smax[2], smax[3]));
    float ir = 1.f / (mx - mn);
    bc[0] = mn; bc[1] = ir;
    irbuf[t] = ir;
    mnirbuf[t] = mn * ir;
  }
  __syncthreads();
  float mn = bc[0], ir = bc[1];
  int cc = ccol[t];
  float wcc = Wlin[cc], bcc = blin[cc], d = Dnz[t];
  for (int n = tid; n < NN; n += 256) {
    float s = (hbuf[n] * wcc + bcc - mn) * ir;
    out[(size_t)t * NN + n] = fmaxf(0.25f, 1.f - expf(-10.f * (s - d)));
  }
}

__global__ void reduce_scalars(const float* __restrict__ ir,
                               const float* __restrict__ mnir,
                               float* __restrict__ scal) {
  int tid = threadIdx.x;  // 512
  int wave = tid >> 6, lane = tid & 63;
  __shared__ float s1[8], s2[8];
  float a = ir[tid], b = mnir[tid];
  a = wred_sum(a); b = wred_sum(b);
  if (lane == 0) { s1[wave] = a; s2[wave] = b; }
  __syncthreads();
  if (tid == 0) {
    float A = 0.f, B = 0.f;
    for (int i = 0; i < 8; i++) { A += s1[i]; B += s2[i]; }
    scal[0] = A; scal[1] = B;
  }
}

__global__ void accum_A(const float* __restrict__ H7,
                        const float* __restrict__ ir,
                        float* __restrict__ Avec) {
  int n = blockIdx.x * 256 + threadIdx.x;
  if (n < NN) {
    float acc = 0.f;
    for (int t = 0; t < QQ; t++) acc += H7[(size_t)t * HPAD + n] * ir[t];
    Avec[n] = acc;
  }
}

__global__ void skills_out(const float* __restrict__ Avec,
                           const float* __restrict__ Wlin,
                           const float* __restrict__ blin,
                           const float* __restrict__ scal,
                           float* __restrict__ out) {  // [NN, CCON]
  int idx = blockIdx.x * 256 + threadIdx.x;
  if (idx < NN * CCON) {
    int n = idx >> 7, c = idx & 127;
    out[idx] = (Wlin[c] * Avec[n] + blin[c] * scal[0] - scal[1]) * (1.f / (float)QQ);
  }
}

extern "C" void kernel_launch(void* const* d_in, const int* in_sizes, int n_in,
                              void* d_out, int out_size, void* d_ws, size_t ws_size,
                              hipStream_t stream) {
  const float* inputs = (const float*)d_in[0];
  const int*   ccol   = (const int*)d_in[1];
  const float* W_inp  = (const float*)d_in[2];
  const float* b_inp  = (const float*)d_in[3];
  const float* W_ih0  = (const float*)d_in[4];
  const float* W_hh0  = (const float*)d_in[5];
  const float* b_ih0  = (const float*)d_in[6];
  const float* b_hh0  = (const float*)d_in[7];
  const float* W_ih   = (const float*)d_in[8];   // [7, 4000, 1000]
  const float* W_hh   = (const float*)d_in[9];   // [7, 4000, 1000]
  const float* b_ih   = (const float*)d_in[10];  // [7, 4000]
  const float* b_hh   = (const float*)d_in[11];  // [7, 4000]
  const float* W_lin  = (const float*)d_in[12];  // [128]
  const float* b_lin  = (const float*)d_in[13];  // [128]
  const float* D_nz   = (const float*)d_in[14];  // [512]

  float* ws = (float*)d_ws;
  float* X    = ws;                        // [512,1024]
  float* P    = X + (size_t)QQ * HHID;     // [512,4000]
  float* H    = P + (size_t)QQ * G4;       // [8][512][1024]
  float* irb  = H + (size_t)LAYERS * QQ * HPAD;  // [512]
  float* mnir = irb + QQ;                  // [512]
  float* Avec = mnir + QQ;                 // [1024]
  float* scal = Avec + 1024;               // [2]
  int*   flags = (int*)(scal + 16);        // [8*64] stamped flags

  float* out_main   = (float*)d_out;            // [512,1000]
  float* out_skills = (float*)d_out + QQ * NN;  // [1000,128]

  // Zero all layer flags (captured in the graph; re-zeroed every replay).
  hipMemsetAsync(flags, 0, LAYERS * 64 * sizeof(int), stream);

  // X = inputs @ W_inp^T + b_inp   (M=512, K=1000, R=1024)
  gemm_nt<<<dim3(HHID / 64, QQ / 64), 256, 0, stream>>>(
      inputs, W_inp, b_inp, nullptr, X, QQ, NN, HHID, NN);
  // P0 = X @ W_ih0^T + b_ih0 + b_hh0   (M=512, K=1024, R=4000)
  gemm_nt<<<dim3((G4 + 63) / 64, QQ / 64), 256, 0, stream>>>(
      X, W_ih0, b_ih0, b_hh0, P, QQ, HHID, G4, HHID);

  // All 8 layers, dataflow-pipelined: critical chain 512+7 stages.
  lstm_pipeline<<<TOTBLK, 1024, 0, stream>>>(P, W_hh0, W_ih, W_hh, b_ih, b_hh,
                                             H, flags);

  float* H7 = H + (size_t)7 * QQ * HPAD;
  epilogue_out<<<QQ, 256, 0, stream>>>(H7, W_lin, b_lin, ccol, D_nz,
                                       out_main, irb, mnir);
  reduce_scalars<<<1, 512, 0, stream>>>(irb, mnir, scal);
  accum_A<<<4, 256, 0, stream>>>(H7, irb, Avec);
  skills_out<<<(NN * CCON) / 256, 256, 0, stream>>>(Avec, W_lin, b_lin, scal,
                                                    out_skills);
}

// Round 8
// 8991.934 us; speedup vs baseline: 1.9715x; 1.9715x over previous
//
#include <hip/hip_runtime.h>
#include <math.h>

#define QQ 512
#define NN 1000
#define HHID 1024
#define HPAD 1024   // padded row stride for h trajectories
#define CCON 128
#define G4 4000
#define LAYERS 8
#define TC 64                       // timestep chunk
#define CHUNKS (QQ / TC)            // 8
#define STAGES (LAYERS + CHUNKS - 1) // 15 anti-diagonal stages
#define LBLK 63     // ceil(1000/16) blocks per layer-pair, 1024 thr, 1 neuron/wave

__device__ inline float wred_min(float v){ for(int o=32;o;o>>=1) v=fminf(v,__shfl_xor(v,o)); return v; }
__device__ inline float wred_max(float v){ for(int o=32;o;o>>=1) v=fmaxf(v,__shfl_xor(v,o)); return v; }
__device__ inline float wred_sum(float v){ for(int o=32;o;o>>=1) v+=__shfl_xor(v,o); return v; }

// ---------------- generic NT GEMM (prologue only) ----------------
__global__ __launch_bounds__(256) void gemm_nt(
    const float* __restrict__ A, const float* __restrict__ B,
    const float* __restrict__ bias1, const float* __restrict__ bias2,
    float* __restrict__ C, int M, int K, int R, int lda) {
  __shared__ float As[16][65];
  __shared__ float Bs[16][65];
  int tid = threadIdx.x;
  int tx = tid & 15, ty = tid >> 4;
  int m0 = blockIdx.y * 64, r0 = blockIdx.x * 64;
  float acc[4][4] = {};
  for (int k0 = 0; k0 < K; k0 += 16) {
#pragma unroll
    for (int i = 0; i < 4; i++) {
      int idx = tid + 256 * i;
      int ml = idx >> 4, kl = idx & 15;
      int m = m0 + ml, k = k0 + kl;
      As[kl][ml] = (m < M && k < K) ? A[(size_t)m * lda + k] : 0.f;
      int r = r0 + ml;
      Bs[kl][ml] = (r < R && k < K) ? B[(size_t)r * K + k] : 0.f;
    }
    __syncthreads();
#pragma unroll
    for (int kk = 0; kk < 16; kk++) {
      float a[4], b[4];
#pragma unroll
      for (int i = 0; i < 4; i++) a[i] = As[kk][ty * 4 + i];
#pragma unroll
      for (int j = 0; j < 4; j++) b[j] = Bs[kk][tx * 4 + j];
#pragma unroll
      for (int i = 0; i < 4; i++)
#pragma unroll
        for (int j = 0; j < 4; j++) acc[i][j] += a[i] * b[j];
    }
    __syncthreads();
  }
#pragma unroll
  for (int i = 0; i < 4; i++) {
    int m = m0 + ty * 4 + i;
    if (m >= M) continue;
#pragma unroll
    for (int j = 0; j < 4; j++) {
      int r = r0 + tx * 4 + j;
      if (r >= R) continue;
      float v = acc[i][j];
      if (bias1) v += bias1[r];
      if (bias2) v += bias2[r];
      C[(size_t)m * R + r] = v;
    }
  }
}

// ---------------- per-stage batched chunk GEMM ----------------
// For each pair (layer l, chunk c) on the anti-diagonal: computes the
// input-side gates Pc[l] = Hin[c-chunk] @ Wih_l^T + b  (M=TC rows, R=G4).
struct GPair { const float* A; const float* B; const float* b1; const float* b2;
               float* C; int K; int lda; };
struct GArgs { GPair p[8]; };

__global__ __launch_bounds__(256) void gemm_stage(GArgs args) {
  GPair pp = args.p[blockIdx.y];
  __shared__ float As[16][65];
  __shared__ float Bs[16][65];
  int tid = threadIdx.x;
  int tx = tid & 15, ty = tid >> 4;
  int r0 = blockIdx.x * 64;
  int K = pp.K, lda = pp.lda;
  float acc[4][4] = {};
  for (int k0 = 0; k0 < K; k0 += 16) {
#pragma unroll
    for (int i = 0; i < 4; i++) {
      int idx = tid + 256 * i;
      int ml = idx >> 4, kl = idx & 15;
      int k = k0 + kl;
      As[kl][ml] = (k < K) ? pp.A[(size_t)ml * lda + k] : 0.f;  // M=TC=64 rows
      int r = r0 + ml;
      Bs[kl][ml] = (r < G4 && k < K) ? pp.B[(size_t)r * K + k] : 0.f;
    }
    __syncthreads();
#pragma unroll
    for (int kk = 0; kk < 16; kk++) {
      float a[4], b[4];
#pragma unroll
      for (int i = 0; i < 4; i++) a[i] = As[kk][ty * 4 + i];
#pragma unroll
      for (int j = 0; j < 4; j++) b[j] = Bs[kk][tx * 4 + j];
#pragma unroll
      for (int i = 0; i < 4; i++)
#pragma unroll
        for (int j = 0; j < 4; j++) acc[i][j] += a[i] * b[j];
    }
    __syncthreads();
  }
#pragma unroll
  for (int i = 0; i < 4; i++) {
    int m = ty * 4 + i;  // < 64 always
#pragma unroll
    for (int j = 0; j < 4; j++) {
      int r = r0 + tx * 4 + j;
      if (r >= G4) continue;
      pp.C[(size_t)m * G4 + r] = acc[i][j] + pp.b1[r] + pp.b2[r];
    }
  }
}

// ---------------- per-stage batched recurrence (TC steps) ----------------
// blockIdx.y = pair (layer,chunk); blockIdx.x = 0..62; wave owns neuron
// n = blockIdx.x*16+wave with its 4 W_hh rows in 64 VGPRs (round-6 scheme:
// LDS h broadcast, stamped per-block flags, relaxed sc1 atomics, NO fences —
// an agent acquire fence is buffer_inv = full L2 invalidate). Cell state is
// saved/restored per chunk via Call. Flags are monotonic across chunks.
struct RPair { const float* Pc; const float* Whh; float* Hout; int* flag;
               float* Call; int t0; };
struct RArgs { RPair p[8]; };

__global__ __launch_bounds__(1024, 4) void lstm_stage(RArgs args) {
  RPair rp = args.p[blockIdx.y];
  __shared__ float hs[1024];
  int tid = threadIdx.x;
  int wave = tid >> 6, lane = tid & 63;
  int n = blockIdx.x * 16 + wave;
  bool active = (n < NN);

  // Preload W_hh rows: wreg[q][it] = Whh[q*1000+n][it*64+lane]
  float wreg[4][16];
  if (active) {
#pragma unroll
    for (int q = 0; q < 4; q++) {
      const float* wrow = rp.Whh + (size_t)(q * NN + n) * NN;
#pragma unroll
      for (int it = 0; it < 16; it++) {
        int k = it * 64 + lane;
        wreg[q][it] = (k < NN) ? wrow[k] : 0.f;
      }
    }
  } else {
#pragma unroll
    for (int q = 0; q < 4; q++)
#pragma unroll
      for (int it = 0; it < 16; it++) wreg[q][it] = 0.f;
  }
  if (tid >= NN) hs[tid] = 0.f;  // zero pad 1000..1023 once

  int t0 = rp.t0;
  float creg = 0.f;
  if (t0 > 0 && active)
    creg = __hip_atomic_load(&rp.Call[n], __ATOMIC_RELAXED,
                             __HIP_MEMORY_SCOPE_AGENT);

  for (int tt = 0; tt < TC; tt++) {
    int t = t0 + tt;
    // Prefetch this step's input gates before waiting (L2 latency overlaps).
    const float* pt = rp.Pc + (size_t)tt * G4;
    float p0 = 0.f, p1 = 0.f, p2 = 0.f, p3 = 0.f;
    if (active) {
      p0 = pt[n]; p1 = pt[NN + n]; p2 = pt[2 * NN + n]; p3 = pt[3 * NN + n];
    }
    if (t > 0) {
      // Wait until all 63 blocks of this layer published h[t-1].
      for (;;) {
        int v = t;
        if (tid < LBLK)
          v = __hip_atomic_load(&rp.flag[tid], __ATOMIC_RELAXED,
                                __HIP_MEMORY_SCOPE_AGENT);
        if (__syncthreads_and(v >= t)) break;
        __builtin_amdgcn_s_sleep(2);
      }
      if (tid < NN)
        hs[tid] = __hip_atomic_load(&rp.Hout[(size_t)(t - 1) * HPAD + tid],
                                    __ATOMIC_RELAXED, __HIP_MEMORY_SCOPE_AGENT);
      __syncthreads();
    }
    if (active) {
      float g0, g1, g2, g3;
      if (t == 0) {
        g0 = p0; g1 = p1; g2 = p2; g3 = p3;
      } else {
        float a0 = 0.f, a1 = 0.f, a2 = 0.f, a3 = 0.f;
#pragma unroll
        for (int it = 0; it < 16; it++) {
          float hv = hs[it * 64 + lane];
          a0 += wreg[0][it] * hv;
          a1 += wreg[1][it] * hv;
          a2 += wreg[2][it] * hv;
          a3 += wreg[3][it] * hv;
        }
#pragma unroll
        for (int o = 32; o; o >>= 1) {
          a0 += __shfl_xor(a0, o);
          a1 += __shfl_xor(a1, o);
          a2 += __shfl_xor(a2, o);
          a3 += __shfl_xor(a3, o);
        }
        g0 = a0 + p0; g1 = a1 + p1; g2 = a2 + p2; g3 = a3 + p3;
      }
      float ii = 1.f / (1.f + expf(-g0));
      float ff = 1.f / (1.f + expf(-g1));
      float gg = tanhf(g2);
      float oo = 1.f / (1.f + expf(-g3));
      creg = ff * creg + ii * gg;
      float h = oo * tanhf(creg);
      if (lane == 0)
        __hip_atomic_store(&rp.Hout[(size_t)t * HPAD + n], h, __ATOMIC_RELAXED,
                           __HIP_MEMORY_SCOPE_AGENT);
    }
    __syncthreads();  // all waves drain vmcnt(0) before s_barrier -> h @ LLC
    if (tid == 0)
      __hip_atomic_store(&rp.flag[blockIdx.x], t + 1, __ATOMIC_RELAXED,
                         __HIP_MEMORY_SCOPE_AGENT);
  }
  // Save cell state for the next chunk of this layer.
  if (active && lane == 0)
    __hip_atomic_store(&rp.Call[n], creg, __ATOMIC_RELAXED,
                       __HIP_MEMORY_SCOPE_AGENT);
}

// ---------------- epilogue ----------------
__global__ __launch_bounds__(256) void epilogue_out(
    const float* __restrict__ H7,   // [QQ, HPAD]
    const float* __restrict__ Wlin, const float* __restrict__ blin,
    const int* __restrict__ ccol, const float* __restrict__ Dnz,
    float* __restrict__ out,        // [QQ, NN]
    float* __restrict__ irbuf, float* __restrict__ mnirbuf) {
  int t = blockIdx.x, tid = threadIdx.x;
  int wave = tid >> 6, lane = tid & 63;
  __shared__ float hbuf[NN];
  __shared__ float smin[4], smax[4];
  __shared__ float bc[2];
  float lmin = 3.4e38f, lmax = -3.4e38f;
  for (int i = tid; i < NN; i += 256) {
    float v = H7[(size_t)t * HPAD + i];
    hbuf[i] = v;
    lmin = fminf(lmin, v); lmax = fmaxf(lmax, v);
  }
  lmin = wred_min(lmin); lmax = wred_max(lmax);
  if (lane == 0) { smin[wave] = lmin; smax[wave] = lmax; }
  __syncthreads();
  if (tid == 0) {
    bc[0] = fminf(fminf(smin[0], smin[1]), fminf(smin[2], smin[3]));
    bc[1] = fmaxf(fmaxf(smax[0], smax[1]), fmaxf(smax[2], smax[3]));
  }
  __syncthreads();
  float hmn = bc[0], hmx = bc[1];
  float clo = 3.4e38f, chi = -3.4e38f;
  if (tid < CCON) {
    float w = Wlin[tid], b = blin[tid];
    clo = b + fminf(w * hmn, w * hmx);
    chi = b + fmaxf(w * hmn, w * hmx);
  }
  clo = wred_min(clo); chi = wred_max(chi);
  __syncthreads();  // smin/smax reused below
  if (lane == 0) { smin[wave] = clo; smax[wave] = chi; }
  __syncthreads();
  if (tid == 0) {
    float mn = fminf(fminf(smin[0], smin[1]), fminf(smin[2], smin[3]));
    float mx = fmaxf(fmaxf(smax[0], smax[1]), fmaxf(smax[2], smax[3]));
    float ir = 1.f / (mx - mn);
    bc[0] = mn; bc[1] = ir;
    irbuf[t] = ir;
    mnirbuf[t] = mn * ir;
  }
  __syncthreads();
  float mn = bc[0], ir = bc[1];
  int cc = ccol[t];
  float wcc = Wlin[cc], bcc = blin[cc], d = Dnz[t];
  for (int n = tid; n < NN; n += 256) {
    float s = (hbuf[n] * wcc + bcc - mn) * ir;
    out[(size_t)t * NN + n] = fmaxf(0.25f, 1.f - expf(-10.f * (s - d)));
  }
}

__global__ void reduce_scalars(const float* __restrict__ ir,
                               const float* __restrict__ mnir,
                               float* __restrict__ scal) {
  int tid = threadIdx.x;  // 512
  int wave = tid >> 6, lane = tid & 63;
  __shared__ float s1[8], s2[8];
  float a = ir[tid], b = mnir[tid];
  a = wred_sum(a); b = wred_sum(b);
  if (lane == 0) { s1[wave] = a; s2[wave] = b; }
  __syncthreads();
  if (tid == 0) {
    float A = 0.f, B = 0.f;
    for (int i = 0; i < 8; i++) { A += s1[i]; B += s2[i]; }
    scal[0] = A; scal[1] = B;
  }
}

__global__ void accum_A(const float* __restrict__ H7,
                        const float* __restrict__ ir,
                        float* __restrict__ Avec) {
  int n = blockIdx.x * 256 + threadIdx.x;
  if (n < NN) {
    float acc = 0.f;
    for (int t = 0; t < QQ; t++) acc += H7[(size_t)t * HPAD + n] * ir[t];
    Avec[n] = acc;
  }
}

__global__ void skills_out(const float* __restrict__ Avec,
                           const float* __restrict__ Wlin,
                           const float* __restrict__ blin,
                           const float* __restrict__ scal,
                           float* __restrict__ out) {  // [NN, CCON]
  int idx = blockIdx.x * 256 + threadIdx.x;
  if (idx < NN * CCON) {
    int n = idx >> 7, c = idx & 127;
    out[idx] = (Wlin[c] * Avec[n] + blin[c] * scal[0] - scal[1]) * (1.f / (float)QQ);
  }
}

extern "C" void kernel_launch(void* const* d_in, const int* in_sizes, int n_in,
                              void* d_out, int out_size, void* d_ws, size_t ws_size,
                              hipStream_t stream) {
  const float* inputs = (const float*)d_in[0];
  const int*   ccol   = (const int*)d_in[1];
  const float* W_inp  = (const float*)d_in[2];
  const float* b_inp  = (const float*)d_in[3];
  const float* W_ih0  = (const float*)d_in[4];
  const float* W_hh0  = (const float*)d_in[5];
  const float* b_ih0  = (const float*)d_in[6];
  const float* b_hh0  = (const float*)d_in[7];
  const float* W_ih   = (const float*)d_in[8];   // [7, 4000, 1000]
  const float* W_hh   = (const float*)d_in[9];   // [7, 4000, 1000]
  const float* b_ih   = (const float*)d_in[10];  // [7, 4000]
  const float* b_hh   = (const float*)d_in[11];  // [7, 4000]
  const float* W_lin  = (const float*)d_in[12];  // [128]
  const float* b_lin  = (const float*)d_in[13];  // [128]
  const float* D_nz   = (const float*)d_in[14];  // [512]

  float* ws = (float*)d_ws;
  float* X    = ws;                           // [512,1024]           2.10 MB
  float* Pc   = X + (size_t)QQ * HHID;        // [8][TC][4000]        8.19 MB
  float* H    = Pc + (size_t)LAYERS * TC * G4;// [8][512][1024]      16.78 MB
  float* Call = H + (size_t)LAYERS * QQ * HPAD; // [8][1024]
  float* irb  = Call + LAYERS * HPAD;         // [512]
  float* mnir = irb + QQ;                     // [512]
  float* Avec = mnir + QQ;                    // [1024]
  float* scal = Avec + 1024;                  // [2] (+pad)
  int*   flags = (int*)(scal + 16);           // [8*64] stamped flags

  float* out_main   = (float*)d_out;            // [512,1000]
  float* out_skills = (float*)d_out + QQ * NN;  // [1000,128]

  // Zero all layer flags (captured in graph; re-zeroed every replay).
  hipMemsetAsync(flags, 0, LAYERS * 64 * sizeof(int), stream);

  // X = inputs @ W_inp^T + b_inp   (M=512, K=1000, R=1024)
  gemm_nt<<<dim3(HHID / 64, QQ / 64), 256, 0, stream>>>(
      inputs, W_inp, b_inp, nullptr, X, QQ, NN, HHID, NN);

  // Anti-diagonal chunked wavefront: stage s handles pairs (l, c=s-l).
  for (int s = 0; s < STAGES; s++) {
    int lmin = (s > LAYERS - 1) ? s - (LAYERS - 1) : 0;
    int lmax = (s < CHUNKS - 1) ? s : CHUNKS - 1;
    // note: l range also capped by layer count
    if (lmax > LAYERS - 1) lmax = LAYERS - 1;
    int np = 0;
    GArgs ga; RArgs ra;
    for (int l = lmin; l <= lmax && l < LAYERS; l++) {
      int c = s - l;
      if (c < 0 || c >= CHUNKS) continue;
      GPair& g = ga.p[np];
      RPair& r = ra.p[np];
      if (l == 0) {
        g.A = X + (size_t)c * TC * HHID; g.B = W_ih0;
        g.b1 = b_ih0; g.b2 = b_hh0; g.K = HHID; g.lda = HHID;
      } else {
        g.A = H + ((size_t)(l - 1) * QQ + (size_t)c * TC) * HPAD;
        g.B = W_ih + (size_t)(l - 1) * G4 * NN;
        g.b1 = b_ih + (size_t)(l - 1) * G4; g.b2 = b_hh + (size_t)(l - 1) * G4;
        g.K = NN; g.lda = HPAD;
      }
      g.C = Pc + (size_t)l * TC * G4;
      r.Pc = Pc + (size_t)l * TC * G4;
      r.Whh = (l == 0) ? W_hh0 : W_hh + (size_t)(l - 1) * G4 * NN;
      r.Hout = H + (size_t)l * QQ * HPAD;
      r.flag = flags + l * 64;
      r.Call = Call + l * HPAD;
      r.t0 = c * TC;
      np++;
    }
    for (int i = np; i < 8; i++) { ga.p[i] = ga.p[0]; ra.p[i] = ra.p[0]; }
    gemm_stage<<<dim3(LBLK, np), 256, 0, stream>>>(ga);
    lstm_stage<<<dim3(LBLK, np), 1024, 0, stream>>>(ra);
  }

  float* H7 = H + (size_t)7 * QQ * HPAD;
  epilogue_out<<<QQ, 256, 0, stream>>>(H7, W_lin, b_lin, ccol, D_nz,
                                       out_main, irb, mnir);
  reduce_scalars<<<1, 512, 0, stream>>>(irb, mnir, scal);
  accum_A<<<4, 256, 0, stream>>>(H7, irb, Avec);
  skills_out<<<(NN * CCON) / 256, 256, 0, stream>>>(Avec, W_lin, b_lin, scal,
                                                    out_skills);
}

// Round 9
// 8922.543 us; speedup vs baseline: 1.9869x; 1.0078x over previous
//
#include <hip/hip_runtime.h>
#include <math.h>

#define QQ 512
#define NN 1000
#define HHID 1024
#define HPAD 1024   // padded row stride for h trajectories
#define CCON 128
#define G4 4000
#define LAYERS 8
#define TC 64                       // timestep chunk
#define CHUNKS (QQ / TC)            // 8
#define STAGES (LAYERS + CHUNKS - 1) // 15 anti-diagonal stages
#define LBLK 63     // ceil(1000/16) blocks per layer-pair, 1024 thr, 1 neuron/wave

__device__ inline float wred_min(float v){ for(int o=32;o;o>>=1) v=fminf(v,__shfl_xor(v,o)); return v; }
__device__ inline float wred_max(float v){ for(int o=32;o;o>>=1) v=fmaxf(v,__shfl_xor(v,o)); return v; }
__device__ inline float wred_sum(float v){ for(int o=32;o;o>>=1) v+=__shfl_xor(v,o); return v; }

// ---------------- generic NT GEMM (prologue only) ----------------
__global__ __launch_bounds__(256) void gemm_nt(
    const float* __restrict__ A, const float* __restrict__ B,
    const float* __restrict__ bias1, const float* __restrict__ bias2,
    float* __restrict__ C, int M, int K, int R, int lda) {
  __shared__ float As[16][65];
  __shared__ float Bs[16][65];
  int tid = threadIdx.x;
  int tx = tid & 15, ty = tid >> 4;
  int m0 = blockIdx.y * 64, r0 = blockIdx.x * 64;
  float acc[4][4] = {};
  for (int k0 = 0; k0 < K; k0 += 16) {
#pragma unroll
    for (int i = 0; i < 4; i++) {
      int idx = tid + 256 * i;
      int ml = idx >> 4, kl = idx & 15;
      int m = m0 + ml, k = k0 + kl;
      As[kl][ml] = (m < M && k < K) ? A[(size_t)m * lda + k] : 0.f;
      int r = r0 + ml;
      Bs[kl][ml] = (r < R && k < K) ? B[(size_t)r * K + k] : 0.f;
    }
    __syncthreads();
#pragma unroll
    for (int kk = 0; kk < 16; kk++) {
      float a[4], b[4];
#pragma unroll
      for (int i = 0; i < 4; i++) a[i] = As[kk][ty * 4 + i];
#pragma unroll
      for (int j = 0; j < 4; j++) b[j] = Bs[kk][tx * 4 + j];
#pragma unroll
      for (int i = 0; i < 4; i++)
#pragma unroll
        for (int j = 0; j < 4; j++) acc[i][j] += a[i] * b[j];
    }
    __syncthreads();
  }
#pragma unroll
  for (int i = 0; i < 4; i++) {
    int m = m0 + ty * 4 + i;
    if (m >= M) continue;
#pragma unroll
    for (int j = 0; j < 4; j++) {
      int r = r0 + tx * 4 + j;
      if (r >= R) continue;
      float v = acc[i][j];
      if (bias1) v += bias1[r];
      if (bias2) v += bias2[r];
      C[(size_t)m * R + r] = v;
    }
  }
}

// ---------------- per-stage batched chunk GEMM ----------------
struct GPair { const float* A; const float* B; const float* b1; const float* b2;
               float* C; int K; int lda; };
struct GArgs { GPair p[8]; };

__global__ __launch_bounds__(256) void gemm_stage(GArgs args) {
  GPair pp = args.p[blockIdx.y];
  __shared__ float As[16][65];
  __shared__ float Bs[16][65];
  int tid = threadIdx.x;
  int tx = tid & 15, ty = tid >> 4;
  int r0 = blockIdx.x * 64;
  int K = pp.K, lda = pp.lda;
  float acc[4][4] = {};
  for (int k0 = 0; k0 < K; k0 += 16) {
#pragma unroll
    for (int i = 0; i < 4; i++) {
      int idx = tid + 256 * i;
      int ml = idx >> 4, kl = idx & 15;
      int k = k0 + kl;
      As[kl][ml] = (k < K) ? pp.A[(size_t)ml * lda + k] : 0.f;  // M=TC=64 rows
      int r = r0 + ml;
      Bs[kl][ml] = (r < G4 && k < K) ? pp.B[(size_t)r * K + k] : 0.f;
    }
    __syncthreads();
#pragma unroll
    for (int kk = 0; kk < 16; kk++) {
      float a[4], b[4];
#pragma unroll
      for (int i = 0; i < 4; i++) a[i] = As[kk][ty * 4 + i];
#pragma unroll
      for (int j = 0; j < 4; j++) b[j] = Bs[kk][tx * 4 + j];
#pragma unroll
      for (int i = 0; i < 4; i++)
#pragma unroll
        for (int j = 0; j < 4; j++) acc[i][j] += a[i] * b[j];
    }
    __syncthreads();
  }
#pragma unroll
  for (int i = 0; i < 4; i++) {
    int m = ty * 4 + i;  // < 64 always
#pragma unroll
    for (int j = 0; j < 4; j++) {
      int r = r0 + tx * 4 + j;
      if (r >= G4) continue;
      pp.C[(size_t)m * G4 + r] = acc[i][j] + pp.b1[r] + pp.b2[r];
    }
  }
}

// ---------------- per-stage batched recurrence (TC steps) ----------------
// Round-8 structure + register-PINNED weights: the asm "+v" pin makes each
// preloaded W_hh element a fresh SSA value the compiler cannot rematerialize
// from memory -> 64 weight floats stay VGPR-resident for all TC steps
// (fixes round-8's LLC weight streaming: VGPR was 52, weights re-read every
// step; with >4MB/XCD working set they streamed from LLC at ~5us/step).
struct RPair { const float* Pc; const float* Whh; float* Hout; int* flag;
               float* Call; int t0; };
struct RArgs { RPair p[8]; };

__global__ __launch_bounds__(1024, 4) void lstm_stage(RArgs args) {
  RPair rp = args.p[blockIdx.y];
  __shared__ float hs[1024];
  int tid = threadIdx.x;
  int wave = tid >> 6, lane = tid & 63;
  int n = blockIdx.x * 16 + wave;
  bool active = (n < NN);

  // Preload W_hh rows: wreg[q][it] = Whh[q*1000+n][it*64+lane]
  float wreg[4][16];
  if (active) {
#pragma unroll
    for (int q = 0; q < 4; q++) {
      const float* wrow = rp.Whh + (size_t)(q * NN + n) * NN;
#pragma unroll
      for (int it = 0; it < 16; it++) {
        int k = it * 64 + lane;
        wreg[q][it] = (k < NN) ? wrow[k] : 0.f;
      }
    }
  } else {
#pragma unroll
    for (int q = 0; q < 4; q++)
#pragma unroll
      for (int it = 0; it < 16; it++) wreg[q][it] = 0.f;
  }
  // PIN: force all 64 weight values live in VGPRs (no remat from memory).
#pragma unroll
  for (int q = 0; q < 4; q++)
#pragma unroll
    for (int it = 0; it < 16; it++)
      asm volatile("" : "+v"(wreg[q][it]));

  if (tid >= NN) hs[tid] = 0.f;  // zero pad 1000..1023 once

  int t0 = rp.t0;
  float creg = 0.f;
  if (t0 > 0 && active)
    creg = __hip_atomic_load(&rp.Call[n], __ATOMIC_RELAXED,
                             __HIP_MEMORY_SCOPE_AGENT);

  for (int tt = 0; tt < TC; tt++) {
    int t = t0 + tt;
    // Prefetch this step's input gates before waiting (L2 latency overlaps).
    const float* pt = rp.Pc + (size_t)tt * G4;
    float p0 = 0.f, p1 = 0.f, p2 = 0.f, p3 = 0.f;
    if (active) {
      p0 = pt[n]; p1 = pt[NN + n]; p2 = pt[2 * NN + n]; p3 = pt[3 * NN + n];
    }
    if (t > 0) {
      // Wait until all 63 blocks of this layer published h[t-1].
      for (;;) {
        int v = t;
        if (tid < LBLK)
          v = __hip_atomic_load(&rp.flag[tid], __ATOMIC_RELAXED,
                                __HIP_MEMORY_SCOPE_AGENT);
        if (__syncthreads_and(v >= t)) break;
        __builtin_amdgcn_s_sleep(2);
      }
      if (tid < NN)
        hs[tid] = __hip_atomic_load(&rp.Hout[(size_t)(t - 1) * HPAD + tid],
                                    __ATOMIC_RELAXED, __HIP_MEMORY_SCOPE_AGENT);
      __syncthreads();
    }
    if (active) {
      float g0, g1, g2, g3;
      if (t == 0) {
        g0 = p0; g1 = p1; g2 = p2; g3 = p3;
      } else {
        float a0 = 0.f, a1 = 0.f, a2 = 0.f, a3 = 0.f;
#pragma unroll
        for (int it = 0; it < 16; it++) {
          float hv = hs[it * 64 + lane];
          a0 += wreg[0][it] * hv;
          a1 += wreg[1][it] * hv;
          a2 += wreg[2][it] * hv;
          a3 += wreg[3][it] * hv;
        }
#pragma unroll
        for (int o = 32; o; o >>= 1) {
          a0 += __shfl_xor(a0, o);
          a1 += __shfl_xor(a1, o);
          a2 += __shfl_xor(a2, o);
          a3 += __shfl_xor(a3, o);
        }
        g0 = a0 + p0; g1 = a1 + p1; g2 = a2 + p2; g3 = a3 + p3;
      }
      float ii = 1.f / (1.f + expf(-g0));
      float ff = 1.f / (1.f + expf(-g1));
      float gg = tanhf(g2);
      float oo = 1.f / (1.f + expf(-g3));
      creg = ff * creg + ii * gg;
      float h = oo * tanhf(creg);
      if (lane == 0)
        __hip_atomic_store(&rp.Hout[(size_t)t * HPAD + n], h, __ATOMIC_RELAXED,
                           __HIP_MEMORY_SCOPE_AGENT);
    }
    __syncthreads();  // all waves drain vmcnt(0) before s_barrier -> h @ LLC
    if (tid == 0)
      __hip_atomic_store(&rp.flag[blockIdx.x], t + 1, __ATOMIC_RELAXED,
                         __HIP_MEMORY_SCOPE_AGENT);
  }
  // Save cell state for the next chunk of this layer.
  if (active && lane == 0)
    __hip_atomic_store(&rp.Call[n], creg, __ATOMIC_RELAXED,
                       __HIP_MEMORY_SCOPE_AGENT);
}

// ---------------- epilogue ----------------
__global__ __launch_bounds__(256) void epilogue_out(
    const float* __restrict__ H7,   // [QQ, HPAD]
    const float* __restrict__ Wlin, const float* __restrict__ blin,
    const int* __restrict__ ccol, const float* __restrict__ Dnz,
    float* __restrict__ out,        // [QQ, NN]
    float* __restrict__ irbuf, float* __restrict__ mnirbuf) {
  int t = blockIdx.x, tid = threadIdx.x;
  int wave = tid >> 6, lane = tid & 63;
  __shared__ float hbuf[NN];
  __shared__ float smin[4], smax[4];
  __shared__ float bc[2];
  float lmin = 3.4e38f, lmax = -3.4e38f;
  for (int i = tid; i < NN; i += 256) {
    float v = H7[(size_t)t * HPAD + i];
    hbuf[i] = v;
    lmin = fminf(lmin, v); lmax = fmaxf(lmax, v);
  }
  lmin = wred_min(lmin); lmax = wred_max(lmax);
  if (lane == 0) { smin[wave] = lmin; smax[wave] = lmax; }
  __syncthreads();
  if (tid == 0) {
    bc[0] = fminf(fminf(smin[0], smin[1]), fminf(smin[2], smin[3]));
    bc[1] = fmaxf(fmaxf(smax[0], smax[1]), fmaxf(smax[2], smax[3]));
  }
  __syncthreads();
  float hmn = bc[0], hmx = bc[1];
  float clo = 3.4e38f, chi = -3.4e38f;
  if (tid < CCON) {
    float w = Wlin[tid], b = blin[tid];
    clo = b + fminf(w * hmn, w * hmx);
    chi = b + fmaxf(w * hmn, w * hmx);
  }
  clo = wred_min(clo); chi = wred_max(chi);
  __syncthreads();  // smin/smax reused below
  if (lane == 0) { smin[wave] = clo; smax[wave] = chi; }
  __syncthreads();
  if (tid == 0) {
    float mn = fminf(fminf(smin[0], smin[1]), fminf(smin[2], smin[3]));
    float mx = fmaxf(fmaxf(smax[0], smax[1]), fmaxf(smax[2], smax[3]));
    float ir = 1.f / (mx - mn);
    bc[0] = mn; bc[1] = ir;
    irbuf[t] = ir;
    mnirbuf[t] = mn * ir;
  }
  __syncthreads();
  float mn = bc[0], ir = bc[1];
  int cc = ccol[t];
  float wcc = Wlin[cc], bcc = blin[cc], d = Dnz[t];
  for (int n = tid; n < NN; n += 256) {
    float s = (hbuf[n] * wcc + bcc - mn) * ir;
    out[(size_t)t * NN + n] = fmaxf(0.25f, 1.f - expf(-10.f * (s - d)));
  }
}

__global__ void reduce_scalars(const float* __restrict__ ir,
                               const float* __restrict__ mnir,
                               float* __restrict__ scal) {
  int tid = threadIdx.x;  // 512
  int wave = tid >> 6, lane = tid & 63;
  __shared__ float s1[8], s2[8];
  float a = ir[tid], b = mnir[tid];
  a = wred_sum(a); b = wred_sum(b);
  if (lane == 0) { s1[wave] = a; s2[wave] = b; }
  __syncthreads();
  if (tid == 0) {
    float A = 0.f, B = 0.f;
    for (int i = 0; i < 8; i++) { A += s1[i]; B += s2[i]; }
    scal[0] = A; scal[1] = B;
  }
}

__global__ void accum_A(const float* __restrict__ H7,
                        const float* __restrict__ ir,
                        float* __restrict__ Avec) {
  int n = blockIdx.x * 256 + threadIdx.x;
  if (n < NN) {
    float acc = 0.f;
    for (int t = 0; t < QQ; t++) acc += H7[(size_t)t * HPAD + n] * ir[t];
    Avec[n] = acc;
  }
}

__global__ void skills_out(const float* __restrict__ Avec,
                           const float* __restrict__ Wlin,
                           const float* __restrict__ blin,
                           const float* __restrict__ scal,
                           float* __restrict__ out) {  // [NN, CCON]
  int idx = blockIdx.x * 256 + threadIdx.x;
  if (idx < NN * CCON) {
    int n = idx >> 7, c = idx & 127;
    out[idx] = (Wlin[c] * Avec[n] + blin[c] * scal[0] - scal[1]) * (1.f / (float)QQ);
  }
}

extern "C" void kernel_launch(void* const* d_in, const int* in_sizes, int n_in,
                              void* d_out, int out_size, void* d_ws, size_t ws_size,
                              hipStream_t stream) {
  const float* inputs = (const float*)d_in[0];
  const int*   ccol   = (const int*)d_in[1];
  const float* W_inp  = (const float*)d_in[2];
  const float* b_inp  = (const float*)d_in[3];
  const float* W_ih0  = (const float*)d_in[4];
  const float* W_hh0  = (const float*)d_in[5];
  const float* b_ih0  = (const float*)d_in[6];
  const float* b_hh0  = (const float*)d_in[7];
  const float* W_ih   = (const float*)d_in[8];   // [7, 4000, 1000]
  const float* W_hh   = (const float*)d_in[9];   // [7, 4000, 1000]
  const float* b_ih   = (const float*)d_in[10];  // [7, 4000]
  const float* b_hh   = (const float*)d_in[11];  // [7, 4000]
  const float* W_lin  = (const float*)d_in[12];  // [128]
  const float* b_lin  = (const float*)d_in[13];  // [128]
  const float* D_nz   = (const float*)d_in[14];  // [512]

  float* ws = (float*)d_ws;
  float* X    = ws;                           // [512,1024]
  float* Pc   = X + (size_t)QQ * HHID;        // [8][TC][4000]
  float* H    = Pc + (size_t)LAYERS * TC * G4;// [8][512][1024]
  float* Call = H + (size_t)LAYERS * QQ * HPAD; // [8][1024]
  float* irb  = Call + LAYERS * HPAD;         // [512]
  float* mnir = irb + QQ;                     // [512]
  float* Avec = mnir + QQ;                    // [1024]
  float* scal = Avec + 1024;                  // [2] (+pad)
  int*   flags = (int*)(scal + 16);           // [8*64] stamped flags

  float* out_main   = (float*)d_out;            // [512,1000]
  float* out_skills = (float*)d_out + QQ * NN;  // [1000,128]

  // Zero all layer flags (captured in graph; re-zeroed every replay).
  hipMemsetAsync(flags, 0, LAYERS * 64 * sizeof(int), stream);

  // X = inputs @ W_inp^T + b_inp   (M=512, K=1000, R=1024)
  gemm_nt<<<dim3(HHID / 64, QQ / 64), 256, 0, stream>>>(
      inputs, W_inp, b_inp, nullptr, X, QQ, NN, HHID, NN);

  // Anti-diagonal chunked wavefront: stage s handles pairs (l, c=s-l).
  for (int s = 0; s < STAGES; s++) {
    int lmin = (s > LAYERS - 1) ? s - (LAYERS - 1) : 0;
    int lmax = (s < CHUNKS - 1) ? s : CHUNKS - 1;
    if (lmax > LAYERS - 1) lmax = LAYERS - 1;
    int np = 0;
    GArgs ga; RArgs ra;
    for (int l = lmin; l <= lmax && l < LAYERS; l++) {
      int c = s - l;
      if (c < 0 || c >= CHUNKS) continue;
      GPair& g = ga.p[np];
      RPair& r = ra.p[np];
      if (l == 0) {
        g.A = X + (size_t)c * TC * HHID; g.B = W_ih0;
        g.b1 = b_ih0; g.b2 = b_hh0; g.K = HHID; g.lda = HHID;
      } else {
        g.A = H + ((size_t)(l - 1) * QQ + (size_t)c * TC) * HPAD;
        g.B = W_ih + (size_t)(l - 1) * G4 * NN;
        g.b1 = b_ih + (size_t)(l - 1) * G4; g.b2 = b_hh + (size_t)(l - 1) * G4;
        g.K = NN; g.lda = HPAD;
      }
      g.C = Pc + (size_t)l * TC * G4;
      r.Pc = Pc + (size_t)l * TC * G4;
      r.Whh = (l == 0) ? W_hh0 : W_hh + (size_t)(l - 1) * G4 * NN;
      r.Hout = H + (size_t)l * QQ * HPAD;
      r.flag = flags + l * 64;
      r.Call = Call + l * HPAD;
      r.t0 = c * TC;
      np++;
    }
    for (int i = np; i < 8; i++) { ga.p[i] = ga.p[0]; ra.p[i] = ra.p[0]; }
    gemm_stage<<<dim3(LBLK, np), 256, 0, stream>>>(ga);
    lstm_stage<<<dim3(LBLK, np), 1024, 0, stream>>>(ra);
  }

  float* H7 = H + (size_t)7 * QQ * HPAD;
  epilogue_out<<<QQ, 256, 0, stream>>>(H7, W_lin, b_lin, ccol, D_nz,
                                       out_main, irb, mnir);
  reduce_scalars<<<1, 512, 0, stream>>>(irb, mnir, scal);
  accum_A<<<4, 256, 0, stream>>>(H7, irb, Avec);
  skills_out<<<(NN * CCON) / 256, 256, 0, stream>>>(Avec, W_lin, b_lin, scal,
                                                    out_skills);
}